// Round 15
// baseline (161.372 us; speedup 1.0000x reference)
//
#include <hip/hip_runtime.h>
#include <hip/hip_fp16.h>
#include <cstdint>
#include <cstddef>

#define BB 4
#define NN 1024
#define EMB_ 64
#define NH_ 8
#define BH_ (BB*NH_)
#define HID_ 256
#define K_ 8
#define NPTS_ 64
#define QB 512   // qkv blocks inside pre_kernel
#define CAP 256  // bucket capacity per (b,row); analysis: max len ~100-120

// ---------------- threefry2x32 (JAX-compatible, 20 rounds) ----------------
__host__ __device__ inline void tf2x32(uint32_t k0, uint32_t k1, uint32_t c0, uint32_t c1,
                                       uint32_t &o0, uint32_t &o1) {
  uint32_t ks2 = k0 ^ k1 ^ 0x1BD11BDAu;
  uint32_t x0 = c0 + k0, x1 = c1 + k1;
#define TFR(r) { x0 += x1; x1 = (x1 << (r)) | (x1 >> (32 - (r))); x1 ^= x0; }
  TFR(13) TFR(15) TFR(26) TFR(6)
  x0 += k1;  x1 += ks2 + 1u;
  TFR(17) TFR(29) TFR(16) TFR(24)
  x0 += ks2; x1 += k0 + 2u;
  TFR(13) TFR(15) TFR(26) TFR(6)
  x0 += k0;  x1 += k1 + 3u;
  TFR(17) TFR(29) TFR(16) TFR(24)
  x0 += k1;  x1 += ks2 + 4u;
  TFR(13) TFR(15) TFR(26) TFR(6)
  x0 += ks2; x1 += k0 + 5u;
#undef TFR
  o0 = x0; o1 = x1;
}

__device__ inline uint32_t tf_bits(uint32_t k0, uint32_t k1, uint32_t idx) {
  uint32_t a, b;
  tf2x32(k0, k1, 0u, idx, a, b);
  return a ^ b;
}

__device__ inline float softplusf(float v) {
  return fmaxf(v, 0.f) + log1pf(expf(-fabsf(v)));
}

// ---------------- K1: fused QKV projection + MLP/points + bucket write -----
// Journal: plain launch_bounds (R7: (256,4) -> spills, ~1 GB scratch traffic).
// #pragma unroll 1 on i4 loop (R6/R9: full unroll -> 256 VGPR, 11% occupancy).
// R15: unroll-1 exposed W-load latency (pre stuck ~90 us, VALUBusy 30%,
// FETCH 3 MB -> latency-bound). Manual depth-1 W prefetch restores pipelining
// at +4-8 VGPR instead of full-unroll's +200.
#define ROWS1 8
__global__ void __launch_bounds__(256) pre_kernel(
    const float* __restrict__ x,
    const float* __restrict__ Wq, const float* __restrict__ Wk, const float* __restrict__ Wv,
    const float* __restrict__ Wp1, const float* __restrict__ bp1,
    const float* __restrict__ Wp2, const float* __restrict__ bp2,
    const float* __restrict__ mvalues,
    float* __restrict__ q, __half* __restrict__ k, __half* __restrict__ v,
    uint32_t* __restrict__ bucket, int* __restrict__ cursor,
    uint32_t kg0, uint32_t kg1, uint32_t kl0, uint32_t kl1) {
  __shared__ float xq[ROWS1][EMB_];
  __shared__ float xs[4][EMB_];
  __shared__ float hs[4][HID_];
  __shared__ float ps[4][16];
  __shared__ float meanv[4][K_], invsig[4][K_];
  __shared__ int flv[4][K_];
  __shared__ int pk[4][NPTS_];

  if (blockIdx.x < QB) {
    // ================= QKV =================
    const int block0 = blockIdx.x * ROWS1;
    const int t = threadIdx.x;
    for (int i = t; i < ROWS1 * EMB_; i += 256) xq[i / EMB_][i % EMB_] = x[(size_t)block0 * EMB_ + i];
    __syncthreads();
    const float qkscale = 0.3535533905932738f; // 64^-0.25

    auto dmatf = [&](const float* __restrict__ W, float* __restrict__ o, float sc) {
      for (int half = 0; half < 2; half++) {
        const int c = half * 256 + t;
        float acc[ROWS1];
#pragma unroll
        for (int r = 0; r < ROWS1; r++) acc[r] = 0.f;
        float w0 = W[0 * 512 + c], w1 = W[1 * 512 + c];
        float w2 = W[2 * 512 + c], w3 = W[3 * 512 + c];
#pragma unroll 1
        for (int i4 = 0; i4 < EMB_; i4 += 4) {
          float nw0 = 0.f, nw1 = 0.f, nw2 = 0.f, nw3 = 0.f;
          if (i4 + 4 < EMB_) {            // prefetch next iter's W (depth 1)
            nw0 = W[(i4 + 4) * 512 + c];
            nw1 = W[(i4 + 5) * 512 + c];
            nw2 = W[(i4 + 6) * 512 + c];
            nw3 = W[(i4 + 7) * 512 + c];
          }
#pragma unroll
          for (int r = 0; r < ROWS1; r++) {
            const float4 xv = *(const float4*)&xq[r][i4];   // ds_read_b128 broadcast
            acc[r] += xv.x * w0 + xv.y * w1 + xv.z * w2 + xv.w * w3;
          }
          w0 = nw0; w1 = nw1; w2 = nw2; w3 = nw3;
        }
        const int h = c >> 6, j = c & 63;
#pragma unroll
        for (int r = 0; r < ROWS1; r++) {
          const int gr = block0 + r;
          const int b = gr >> 10, n = gr & 1023;
          o[(((size_t)(b * NH_ + h) * NN + n)) * EMB_ + j] = acc[r] * sc;
        }
      }
    };
    auto dmath = [&](const float* __restrict__ W, __half* __restrict__ o, float sc) {
      for (int half = 0; half < 2; half++) {
        const int c = half * 256 + t;
        float acc[ROWS1];
#pragma unroll
        for (int r = 0; r < ROWS1; r++) acc[r] = 0.f;
        float w0 = W[0 * 512 + c], w1 = W[1 * 512 + c];
        float w2 = W[2 * 512 + c], w3 = W[3 * 512 + c];
#pragma unroll 1
        for (int i4 = 0; i4 < EMB_; i4 += 4) {
          float nw0 = 0.f, nw1 = 0.f, nw2 = 0.f, nw3 = 0.f;
          if (i4 + 4 < EMB_) {
            nw0 = W[(i4 + 4) * 512 + c];
            nw1 = W[(i4 + 5) * 512 + c];
            nw2 = W[(i4 + 6) * 512 + c];
            nw3 = W[(i4 + 7) * 512 + c];
          }
#pragma unroll
          for (int r = 0; r < ROWS1; r++) {
            const float4 xv = *(const float4*)&xq[r][i4];
            acc[r] += xv.x * w0 + xv.y * w1 + xv.z * w2 + xv.w * w3;
          }
          w0 = nw0; w1 = nw1; w2 = nw2; w3 = nw3;
        }
        const int h = c >> 6, j = c & 63;
#pragma unroll
        for (int r = 0; r < ROWS1; r++) {
          const int gr = block0 + r;
          const int b = gr >> 10, n = gr & 1023;
          o[(((size_t)(b * NH_ + h) * NN + n)) * EMB_ + j] = __float2half(acc[r] * sc);
        }
      }
    };
    dmatf(Wq, q, qkscale);
    dmath(Wk, k, qkscale);
    dmath(Wv, v, 1.0f);
    return;
  }

  // ================= points (4 bn per block; round-5 proven path) =========
  const int w = threadIdx.x >> 6, lane = threadIdx.x & 63;
  const int bn = (blockIdx.x - QB) * 4 + w;
  const int b = bn >> 10, n = bn & 1023;

  xs[w][lane] = x[(size_t)bn * EMB_ + lane];
  __syncthreads();

#pragma unroll
  for (int cc = 0; cc < 4; cc++) {
    const int c = cc * 64 + lane;
    float a = bp1[c];
    for (int i = 0; i < EMB_; i++) a += xs[w][i] * Wp1[i * HID_ + c];
    hs[w][c] = fmaxf(a, 0.f);
  }
  __syncthreads();

  if (lane < 16) {
    float a = bp2[lane];
    for (int c = 0; c < HID_; c++) a += hs[w][c] * Wp2[c * 16 + lane];
    ps[w][lane] = a;
  }
  __syncthreads();

  if (lane < K_) {
    const float rm = ps[w][lane], rs = ps[w][K_ + lane];
    float mean = (float)n - softplusf(rm);
    mean = fminf(fmaxf(mean, 0.f), (float)(NN - 1));
    const float sig = softplusf(rs + 2.0f) + 1e-6f;
    meanv[w][lane] = mean;
    invsig[w][lane] = 1.f / sig;
    flv[w][lane] = (int)floorf(mean);
  }
  __syncthreads();

  const int kk = lane >> 3, j = lane & 7;
  const int fl = flv[w][kk];
  int row, col;
  if (j < 4) {
    row = fl + (j >> 1);
    col = fl + (j & 1);
  } else if (j < 6) {
    const int g = j - 4;
    const uint32_t base = ((uint32_t)(bn * K_ + kk) * 2u + (uint32_t)g) * 2u;
    row = (int)(tf_bits(kg0, kg1, base + 0u) & 1023u);
    col = (int)(tf_bits(kg0, kg1, base + 1u) & 1023u);
  } else {
    const int a = j - 6;
    const uint32_t base = ((uint32_t)(bn * K_ + kk) * 2u + (uint32_t)a) * 2u;
    row = fl - 1 + (int)(tf_bits(kl0, kl1, base + 0u) & 1u);
    col = fl - 1 + (int)(tf_bits(kl0, kl1, base + 1u) & 1u);
  }
  row = min(max(row, 0), NN - 1);
  col = min(max(col, 0), NN - 1);
  const int packed = (row << 16) | col;
  pk[w][lane] = packed;
  __syncthreads();

  bool dup = false;
  for (int p2 = 0; p2 < lane; p2++)
    if (pk[w][p2] == packed) dup = true;

  const float frow = (float)row, fcol = (float)col;
  float dens[K_];
#pragma unroll
  for (int qd = 0; qd < K_; qd++) {
    const float dx = (frow - meanv[w][qd]) * invsig[w][qd];
    const float dy = (fcol - meanv[w][qd]) * invsig[w][qd];
    dens[qd] = dup ? 0.f : expf(-0.5f * (dx * dx + dy * dy));
  }
  float wsum = 0.f;
#pragma unroll
  for (int qd = 0; qd < K_; qd++) {
    float s = dens[qd];
    for (int d = 1; d < 64; d <<= 1) s += __shfl_xor(s, d);
    wsum += dens[qd] / s;
  }
  const float wgt = mvalues[n] * wsum;

  // direct bucket write (replaces prc/pw + scan + scatter)
  const int seg = b * NN + row;
  const uint32_t payload = ((uint32_t)col << 16) |
                           (uint32_t)__half_as_ushort(__float2half(wgt));
  const int pos = atomicAdd(&cursor[seg], 1);
  if (pos < CAP) bucket[((size_t)seg << 8) + pos] = payload;
}

// ---------------- K2: flash segment softmax + fused output projection ------
// __launch_bounds__(512, 6): R12 (no bound) -> VGPR 68, occupancy 20%, 137 us.
// R13 (512,8) -> VGPR 32, spills (WRITE_SIZE 1->55 MB). (512,6) landed it.
__global__ void __launch_bounds__(512, 6) attn_out_kernel(
    const float* __restrict__ q, const __half* __restrict__ k, const __half* __restrict__ v,
    const int* __restrict__ cursor, const uint32_t* __restrict__ bucket,
    const float* __restrict__ Wu, const float* __restrict__ bu,
    float* __restrict__ out) {
  __shared__ float qs[NH_][EMB_];
  __shared__ float ps_lds[NH_][64];
  __shared__ int   cs_lds[NH_][64];
  __shared__ float ao[NH_][EMB_];
  __shared__ float op[NH_][EMB_];

  const int xcd = blockIdx.x & 7;
  const int rank = blockIdx.x >> 3;        // 0..511
  const int b = xcd >> 1;                  // 2 XCDs per batch
  const int row = (rank << 1) | (xcd & 1); // 0..1023

  const int h = threadIdx.x >> 6, lane = threadIdx.x & 63;
  const int bh = b * NH_ + h;

  const __half* __restrict__ kb = k + (size_t)bh * NN * EMB_;
  const __half* __restrict__ vb = v + (size_t)bh * NN * EMB_;
  const int seg = b * NN + row;
  const uint32_t* __restrict__ sp = bucket + ((size_t)seg << 8);

  qs[h][lane] = q[((size_t)bh * NN + row) * EMB_ + lane];
  const int len = min(cursor[seg], CAP);
  __syncthreads();

  float m = -INFINITY, Z = 0.f, acc = 0.f;

  for (int cb = 0; cb < len; cb += 64) {
    const int e = cb + lane;
    float logit = -INFINITY;
    int col = 0;
    if (e < len) {
      const uint32_t u = sp[e];
      col = (int)(u >> 16);
      const float wv = __half2float(__ushort_as_half((unsigned short)(u & 0xFFFFu)));
      const float4* __restrict__ kp4 = (const float4*)(kb + (size_t)col * EMB_);
      const float4* __restrict__ qp = (const float4*)qs[h];
      float dot = 0.f;
#pragma unroll
      for (int i = 0; i < 8; i++) {
        const float4 raw = kp4[i];
        const __half2* h2 = (const __half2*)&raw;   // 4 half2 = 8 halves
        const float4 qa = qp[i * 2];
        const float4 qb2 = qp[i * 2 + 1];
        const float2 f0 = __half22float2(h2[0]);
        const float2 f1 = __half22float2(h2[1]);
        const float2 f2 = __half22float2(h2[2]);
        const float2 f3 = __half22float2(h2[3]);
        dot += qa.x * f0.x + qa.y * f0.y + qa.z * f1.x + qa.w * f1.y;
        dot += qb2.x * f2.x + qb2.y * f2.y + qb2.z * f3.x + qb2.w * f3.y;
      }
      logit = wv * dot;
    }
    float cm = logit;
#pragma unroll
    for (int d = 1; d < 64; d <<= 1) cm = fmaxf(cm, __shfl_xor(cm, d));
    const float nm = fmaxf(m, cm);
    const float scale = expf(m - nm);            // 0 when m was -inf
    const float p = expf(logit - nm);            // 0 for e >= len
    float zs = p;
#pragma unroll
    for (int d = 1; d < 64; d <<= 1) zs += __shfl_xor(zs, d);
    Z = Z * scale + zs;
    m = nm;

    ps_lds[h][lane] = p;
    cs_lds[h][lane] = col;

    acc *= scale;
    const int lim = len - cb;
#pragma unroll
    for (int g = 0; g < 8; g++) {
      if (g * 8 < lim) {
#pragma unroll
        for (int u8 = 0; u8 < 8; u8++) {
          const int ee = g * 8 + u8;
          acc += ps_lds[h][ee] * __half2float(vb[(size_t)cs_lds[h][ee] * EMB_ + lane]);
        }
      }
    }
  }

  ao[h][lane] = (len > 0) ? acc / Z : 0.f;
  __syncthreads();

  float s = 0.f;
  const float* __restrict__ wu_h = Wu + (size_t)(h * 64) * EMB_;
#pragma unroll
  for (int d = 0; d < 64; d++)
    s += ao[h][d] * wu_h[d * EMB_ + lane];
  op[h][lane] = s;
  __syncthreads();

  if (h == 0) {
    float t = bu[lane];
#pragma unroll
    for (int hh = 0; hh < NH_; hh++) t += op[hh][lane];
    out[(size_t)(b * NN + row) * EMB_ + lane] = t;
  }
}

// ---------------- host ----------------
extern "C" void kernel_launch(void* const* d_in, const int* in_sizes, int n_in,
                              void* d_out, int out_size, void* d_ws, size_t ws_size,
                              hipStream_t stream) {
  const float* x   = (const float*)d_in[0];
  const float* Wq  = (const float*)d_in[1];
  const float* Wk  = (const float*)d_in[2];
  const float* Wv  = (const float*)d_in[3];
  const float* Wu  = (const float*)d_in[4];
  const float* bu  = (const float*)d_in[5];
  const float* Wp1 = (const float*)d_in[6];
  const float* bp1 = (const float*)d_in[7];
  const float* Wp2 = (const float*)d_in[8];
  const float* bp2 = (const float*)d_in[9];
  const float* mv  = (const float*)d_in[10];
  float* out = (float*)d_out;

  char* ws = (char*)d_ws;
  size_t off = 0;
  auto alloc = [&](size_t bytes) -> void* {
    void* p = ws + off;
    off += (bytes + 255) & ~(size_t)255;
    return p;
  };
  const size_t QF = (size_t)BH_ * NN * EMB_ * sizeof(float);   // 8 MB
  const size_t QH = (size_t)BH_ * NN * EMB_ * sizeof(__half);  // 4 MB
  float*    q      = (float*)   alloc(QF);
  __half*   k      = (__half*)  alloc(QH);
  __half*   v      = (__half*)  alloc(QH);
  uint32_t* bucket = (uint32_t*)alloc((size_t)BB * NN * CAP * sizeof(uint32_t)); // 4 MB
  int*      cursor = (int*)     alloc((size_t)BB * NN * sizeof(int));
  if (off > ws_size) return;

  uint32_t kgA, kgB, klA, klB;
  tf2x32(0u, 42u, 0u, 0u, kgA, kgB);  // kg
  tf2x32(0u, 42u, 0u, 1u, klA, klB);  // kl
  uint32_t kg2A, kg2B, kl2A, kl2B;
  tf2x32(kgA, kgB, 0u, 1u, kg2A, kg2B); // split(kg)[1]
  tf2x32(klA, klB, 0u, 1u, kl2A, kl2B); // split(kl)[1]

  hipMemsetAsync(cursor, 0, (size_t)BB * NN * sizeof(int), stream);

  pre_kernel<<<QB + (BB * NN) / 4, 256, 0, stream>>>(
      x, Wq, Wk, Wv, Wp1, bp1, Wp2, bp2, mv, q, k, v, bucket, cursor,
      kg2A, kg2B, kl2A, kl2B);
  attn_out_kernel<<<BB * NN, 512, 0, stream>>>(q, k, v, cursor, bucket,
                                               Wu, bu, out);
}

// Round 16
// 157.495 us; speedup vs baseline: 1.0246x; 1.0246x over previous
//
#include <hip/hip_runtime.h>
#include <hip/hip_fp16.h>
#include <cstdint>
#include <cstddef>

#define BB 4
#define NN 1024
#define EMB_ 64
#define NH_ 8
#define BH_ (BB*NH_)
#define HID_ 256
#define K_ 8
#define NPTS_ 64
#define ROWS1 4
#define QB 1024  // qkv blocks (4096 rows / ROWS1)
#define CAP 256  // bucket capacity per (b,row)

// ---------------- threefry2x32 (JAX-compatible, 20 rounds) ----------------
__host__ __device__ inline void tf2x32(uint32_t k0, uint32_t k1, uint32_t c0, uint32_t c1,
                                       uint32_t &o0, uint32_t &o1) {
  uint32_t ks2 = k0 ^ k1 ^ 0x1BD11BDAu;
  uint32_t x0 = c0 + k0, x1 = c1 + k1;
#define TFR(r) { x0 += x1; x1 = (x1 << (r)) | (x1 >> (32 - (r))); x1 ^= x0; }
  TFR(13) TFR(15) TFR(26) TFR(6)
  x0 += k1;  x1 += ks2 + 1u;
  TFR(17) TFR(29) TFR(16) TFR(24)
  x0 += ks2; x1 += k0 + 2u;
  TFR(13) TFR(15) TFR(26) TFR(6)
  x0 += k0;  x1 += k1 + 3u;
  TFR(17) TFR(29) TFR(16) TFR(24)
  x0 += k1;  x1 += ks2 + 4u;
  TFR(13) TFR(15) TFR(26) TFR(6)
  x0 += ks2; x1 += k0 + 5u;
#undef TFR
  o0 = x0; o1 = x1;
}

__device__ inline uint32_t tf_bits(uint32_t k0, uint32_t k1, uint32_t idx) {
  uint32_t a, b;
  tf2x32(k0, k1, 0u, idx, a, b);
  return a ^ b;
}

__device__ inline float softplusf(float v) {
  return fmaxf(v, 0.f) + log1pf(expf(-fabsf(v)));
}

// ---------------- K1: fused QKV projection + MLP/points + bucket write -----
// Journal: plain launch_bounds (R7: (256,4) -> spills). #pragma unroll 1
// (R6/R9: full unroll -> 256 VGPR). R15: W-prefetch neutral -> bottleneck is
// the LDS pipe, not W latency. R16: fuse Q,K,V into ONE pass over the x-tile
// (ROWS1=4, acc[3][4]): ds_read_b128 768 -> 128 per thread (6x). R6's blowup
// was ROWS1=8 (24 acc) + full unroll; 12 acc + unroll-1 stays bounded.
__global__ void __launch_bounds__(256) pre_kernel(
    const float* __restrict__ x,
    const float* __restrict__ Wq, const float* __restrict__ Wk, const float* __restrict__ Wv,
    const float* __restrict__ Wp1, const float* __restrict__ bp1,
    const float* __restrict__ Wp2, const float* __restrict__ bp2,
    const float* __restrict__ mvalues,
    float* __restrict__ q, __half* __restrict__ k, __half* __restrict__ v,
    uint32_t* __restrict__ bucket, int* __restrict__ cursor,
    uint32_t kg0, uint32_t kg1, uint32_t kl0, uint32_t kl1) {
  __shared__ float xq[ROWS1][EMB_];
  __shared__ float xs[4][EMB_];
  __shared__ float hs[4][HID_];
  __shared__ float ps[4][16];
  __shared__ float meanv[4][K_], invsig[4][K_];
  __shared__ int flv[4][K_];
  __shared__ int pk[4][NPTS_];

  if (blockIdx.x < QB) {
    // ================= QKV: one pass over x-tile, 3 matrices =============
    const int block0 = blockIdx.x * ROWS1;
    const int t = threadIdx.x;
    xq[t >> 6][t & 63] = x[(size_t)block0 * EMB_ + t];   // 4x64 tile
    __syncthreads();
    const float qkscale = 0.3535533905932738f; // 64^-0.25

    for (int half = 0; half < 2; half++) {
      const int c = half * 256 + t;
      float aq[ROWS1], ak[ROWS1], av[ROWS1];
#pragma unroll
      for (int r = 0; r < ROWS1; r++) { aq[r] = 0.f; ak[r] = 0.f; av[r] = 0.f; }
#pragma unroll 1
      for (int i4 = 0; i4 < EMB_; i4 += 4) {
        const float q0 = Wq[(i4 + 0) * 512 + c];
        const float q1 = Wq[(i4 + 1) * 512 + c];
        const float q2 = Wq[(i4 + 2) * 512 + c];
        const float q3 = Wq[(i4 + 3) * 512 + c];
        const float k0 = Wk[(i4 + 0) * 512 + c];
        const float k1 = Wk[(i4 + 1) * 512 + c];
        const float k2 = Wk[(i4 + 2) * 512 + c];
        const float k3 = Wk[(i4 + 3) * 512 + c];
        const float v0 = Wv[(i4 + 0) * 512 + c];
        const float v1 = Wv[(i4 + 1) * 512 + c];
        const float v2 = Wv[(i4 + 2) * 512 + c];
        const float v3 = Wv[(i4 + 3) * 512 + c];
#pragma unroll
        for (int r = 0; r < ROWS1; r++) {
          const float4 xv = *(const float4*)&xq[r][i4];   // ds_read_b128, read ONCE
          aq[r] += xv.x * q0 + xv.y * q1 + xv.z * q2 + xv.w * q3;
          ak[r] += xv.x * k0 + xv.y * k1 + xv.z * k2 + xv.w * k3;
          av[r] += xv.x * v0 + xv.y * v1 + xv.z * v2 + xv.w * v3;
        }
      }
      const int h = c >> 6, j = c & 63;
#pragma unroll
      for (int r = 0; r < ROWS1; r++) {
        const int gr = block0 + r;
        const int b = gr >> 10, n = gr & 1023;
        const size_t o = ((size_t)(b * NH_ + h) * NN + n) * EMB_ + j;
        q[o] = aq[r] * qkscale;
        k[o] = __float2half(ak[r] * qkscale);
        v[o] = __float2half(av[r]);
      }
    }
    return;
  }

  // ================= points (4 bn per block; round-5 proven path) =========
  const int w = threadIdx.x >> 6, lane = threadIdx.x & 63;
  const int bn = (blockIdx.x - QB) * 4 + w;
  const int b = bn >> 10, n = bn & 1023;

  xs[w][lane] = x[(size_t)bn * EMB_ + lane];
  __syncthreads();

#pragma unroll
  for (int cc = 0; cc < 4; cc++) {
    const int c = cc * 64 + lane;
    float a = bp1[c];
    for (int i = 0; i < EMB_; i++) a += xs[w][i] * Wp1[i * HID_ + c];
    hs[w][c] = fmaxf(a, 0.f);
  }
  __syncthreads();

  if (lane < 16) {
    float a = bp2[lane];
    for (int c = 0; c < HID_; c++) a += hs[w][c] * Wp2[c * 16 + lane];
    ps[w][lane] = a;
  }
  __syncthreads();

  if (lane < K_) {
    const float rm = ps[w][lane], rs = ps[w][K_ + lane];
    float mean = (float)n - softplusf(rm);
    mean = fminf(fmaxf(mean, 0.f), (float)(NN - 1));
    const float sig = softplusf(rs + 2.0f) + 1e-6f;
    meanv[w][lane] = mean;
    invsig[w][lane] = 1.f / sig;
    flv[w][lane] = (int)floorf(mean);
  }
  __syncthreads();

  const int kk = lane >> 3, j = lane & 7;
  const int fl = flv[w][kk];
  int row, col;
  if (j < 4) {
    row = fl + (j >> 1);
    col = fl + (j & 1);
  } else if (j < 6) {
    const int g = j - 4;
    const uint32_t base = ((uint32_t)(bn * K_ + kk) * 2u + (uint32_t)g) * 2u;
    row = (int)(tf_bits(kg0, kg1, base + 0u) & 1023u);
    col = (int)(tf_bits(kg0, kg1, base + 1u) & 1023u);
  } else {
    const int a = j - 6;
    const uint32_t base = ((uint32_t)(bn * K_ + kk) * 2u + (uint32_t)a) * 2u;
    row = fl - 1 + (int)(tf_bits(kl0, kl1, base + 0u) & 1u);
    col = fl - 1 + (int)(tf_bits(kl0, kl1, base + 1u) & 1u);
  }
  row = min(max(row, 0), NN - 1);
  col = min(max(col, 0), NN - 1);
  const int packed = (row << 16) | col;
  pk[w][lane] = packed;
  __syncthreads();

  bool dup = false;
  for (int p2 = 0; p2 < lane; p2++)
    if (pk[w][p2] == packed) dup = true;

  const float frow = (float)row, fcol = (float)col;
  float dens[K_];
#pragma unroll
  for (int qd = 0; qd < K_; qd++) {
    const float dx = (frow - meanv[w][qd]) * invsig[w][qd];
    const float dy = (fcol - meanv[w][qd]) * invsig[w][qd];
    dens[qd] = dup ? 0.f : expf(-0.5f * (dx * dx + dy * dy));
  }
  float wsum = 0.f;
#pragma unroll
  for (int qd = 0; qd < K_; qd++) {
    float s = dens[qd];
    for (int d = 1; d < 64; d <<= 1) s += __shfl_xor(s, d);
    wsum += dens[qd] / s;
  }
  const float wgt = mvalues[n] * wsum;

  // direct bucket write (replaces prc/pw + scan + scatter)
  const int seg = b * NN + row;
  const uint32_t payload = ((uint32_t)col << 16) |
                           (uint32_t)__half_as_ushort(__float2half(wgt));
  const int pos = atomicAdd(&cursor[seg], 1);
  if (pos < CAP) bucket[((size_t)seg << 8) + pos] = payload;
}

// ---------------- K2: flash segment softmax + fused output projection ------
// __launch_bounds__(512, 6): R12 (no bound) -> VGPR 68, occupancy 20%, 137 us.
// R13 (512,8) -> VGPR 32, spills (WRITE_SIZE 1->55 MB). (512,6) landed it.
__global__ void __launch_bounds__(512, 6) attn_out_kernel(
    const float* __restrict__ q, const __half* __restrict__ k, const __half* __restrict__ v,
    const int* __restrict__ cursor, const uint32_t* __restrict__ bucket,
    const float* __restrict__ Wu, const float* __restrict__ bu,
    float* __restrict__ out) {
  __shared__ float qs[NH_][EMB_];
  __shared__ float ps_lds[NH_][64];
  __shared__ int   cs_lds[NH_][64];
  __shared__ float ao[NH_][EMB_];
  __shared__ float op[NH_][EMB_];

  const int xcd = blockIdx.x & 7;
  const int rank = blockIdx.x >> 3;        // 0..511
  const int b = xcd >> 1;                  // 2 XCDs per batch
  const int row = (rank << 1) | (xcd & 1); // 0..1023

  const int h = threadIdx.x >> 6, lane = threadIdx.x & 63;
  const int bh = b * NH_ + h;

  const __half* __restrict__ kb = k + (size_t)bh * NN * EMB_;
  const __half* __restrict__ vb = v + (size_t)bh * NN * EMB_;
  const int seg = b * NN + row;
  const uint32_t* __restrict__ sp = bucket + ((size_t)seg << 8);

  qs[h][lane] = q[((size_t)bh * NN + row) * EMB_ + lane];
  const int len = min(cursor[seg], CAP);
  __syncthreads();

  float m = -INFINITY, Z = 0.f, acc = 0.f;

  for (int cb = 0; cb < len; cb += 64) {
    const int e = cb + lane;
    float logit = -INFINITY;
    int col = 0;
    if (e < len) {
      const uint32_t u = sp[e];
      col = (int)(u >> 16);
      const float wv = __half2float(__ushort_as_half((unsigned short)(u & 0xFFFFu)));
      const float4* __restrict__ kp4 = (const float4*)(kb + (size_t)col * EMB_);
      const float4* __restrict__ qp = (const float4*)qs[h];
      float dot = 0.f;
#pragma unroll
      for (int i = 0; i < 8; i++) {
        const float4 raw = kp4[i];
        const __half2* h2 = (const __half2*)&raw;   // 4 half2 = 8 halves
        const float4 qa = qp[i * 2];
        const float4 qb2 = qp[i * 2 + 1];
        const float2 f0 = __half22float2(h2[0]);
        const float2 f1 = __half22float2(h2[1]);
        const float2 f2 = __half22float2(h2[2]);
        const float2 f3 = __half22float2(h2[3]);
        dot += qa.x * f0.x + qa.y * f0.y + qa.z * f1.x + qa.w * f1.y;
        dot += qb2.x * f2.x + qb2.y * f2.y + qb2.z * f3.x + qb2.w * f3.y;
      }
      logit = wv * dot;
    }
    float cm = logit;
#pragma unroll
    for (int d = 1; d < 64; d <<= 1) cm = fmaxf(cm, __shfl_xor(cm, d));
    const float nm = fmaxf(m, cm);
    const float scale = expf(m - nm);            // 0 when m was -inf
    const float p = expf(logit - nm);            // 0 for e >= len
    float zs = p;
#pragma unroll
    for (int d = 1; d < 64; d <<= 1) zs += __shfl_xor(zs, d);
    Z = Z * scale + zs;
    m = nm;

    ps_lds[h][lane] = p;
    cs_lds[h][lane] = col;

    acc *= scale;
    const int lim = len - cb;
#pragma unroll
    for (int g = 0; g < 8; g++) {
      if (g * 8 < lim) {
#pragma unroll
        for (int u8 = 0; u8 < 8; u8++) {
          const int ee = g * 8 + u8;
          acc += ps_lds[h][ee] * __half2float(vb[(size_t)cs_lds[h][ee] * EMB_ + lane]);
        }
      }
    }
  }

  ao[h][lane] = (len > 0) ? acc / Z : 0.f;
  __syncthreads();

  float s = 0.f;
  const float* __restrict__ wu_h = Wu + (size_t)(h * 64) * EMB_;
#pragma unroll
  for (int d = 0; d < 64; d++)
    s += ao[h][d] * wu_h[d * EMB_ + lane];
  op[h][lane] = s;
  __syncthreads();

  if (h == 0) {
    float t = bu[lane];
#pragma unroll
    for (int hh = 0; hh < NH_; hh++) t += op[hh][lane];
    out[(size_t)(b * NN + row) * EMB_ + lane] = t;
  }
}

// ---------------- host ----------------
extern "C" void kernel_launch(void* const* d_in, const int* in_sizes, int n_in,
                              void* d_out, int out_size, void* d_ws, size_t ws_size,
                              hipStream_t stream) {
  const float* x   = (const float*)d_in[0];
  const float* Wq  = (const float*)d_in[1];
  const float* Wk  = (const float*)d_in[2];
  const float* Wv  = (const float*)d_in[3];
  const float* Wu  = (const float*)d_in[4];
  const float* bu  = (const float*)d_in[5];
  const float* Wp1 = (const float*)d_in[6];
  const float* bp1 = (const float*)d_in[7];
  const float* Wp2 = (const float*)d_in[8];
  const float* bp2 = (const float*)d_in[9];
  const float* mv  = (const float*)d_in[10];
  float* out = (float*)d_out;

  char* ws = (char*)d_ws;
  size_t off = 0;
  auto alloc = [&](size_t bytes) -> void* {
    void* p = ws + off;
    off += (bytes + 255) & ~(size_t)255;
    return p;
  };
  const size_t QF = (size_t)BH_ * NN * EMB_ * sizeof(float);   // 8 MB
  const size_t QH = (size_t)BH_ * NN * EMB_ * sizeof(__half);  // 4 MB
  float*    q      = (float*)   alloc(QF);
  __half*   k      = (__half*)  alloc(QH);
  __half*   v      = (__half*)  alloc(QH);
  uint32_t* bucket = (uint32_t*)alloc((size_t)BB * NN * CAP * sizeof(uint32_t)); // 4 MB
  int*      cursor = (int*)     alloc((size_t)BB * NN * sizeof(int));
  if (off > ws_size) return;

  uint32_t kgA, kgB, klA, klB;
  tf2x32(0u, 42u, 0u, 0u, kgA, kgB);  // kg
  tf2x32(0u, 42u, 0u, 1u, klA, klB);  // kl
  uint32_t kg2A, kg2B, kl2A, kl2B;
  tf2x32(kgA, kgB, 0u, 1u, kg2A, kg2B); // split(kg)[1]
  tf2x32(klA, klB, 0u, 1u, kl2A, kl2B); // split(kl)[1]

  hipMemsetAsync(cursor, 0, (size_t)BB * NN * sizeof(int), stream);

  pre_kernel<<<QB + (BB * NN) / 4, 256, 0, stream>>>(
      x, Wq, Wk, Wv, Wp1, bp1, Wp2, bp2, mv, q, k, v, bucket, cursor,
      kg2A, kg2B, kl2A, kl2B);
  attn_out_kernel<<<BB * NN, 512, 0, stream>>>(q, k, v, cursor, bucket,
                                               Wu, bu, out);
}